// Round 4
// baseline (182.674 us; speedup 1.0000x reference)
//
#include <hip/hip_runtime.h>
#include <hip/hip_bf16.h>

typedef __bf16 bf16;
typedef __bf16 bf16x4 __attribute__((ext_vector_type(4)));
typedef __bf16 bf16x8 __attribute__((ext_vector_type(8)));
typedef float floatx4 __attribute__((ext_vector_type(4)));
typedef short short4_ __attribute__((ext_vector_type(4)));

#define B_ 2
#define T_ 2048
#define C_ 1024
#define H_ 16
#define D_ 64
#define M_ 4096
#define QK_LD 2048

__device__ __forceinline__ void load_lds16(const void* g, void* l) {
  __builtin_amdgcn_global_load_lds(
      (const __attribute__((address_space(1))) unsigned int*)g,
      (__attribute__((address_space(3))) unsigned int*)l, 16, 0, 0);
}

// 16x16x16 bf16 MFMA: A[m=l16][k=quad*4+j], B[k=quad*4+j][n=l16] — the B
// layout matches the C/D layout of a swapped QK^T (in-register softmax->PV).
__device__ __forceinline__ floatx4 mfma16(bf16x4 a, bf16x4 b, floatx4 c) {
#if __has_builtin(__builtin_amdgcn_mfma_f32_16x16x16_bf16)
  return __builtin_amdgcn_mfma_f32_16x16x16_bf16(a, b, c, 0, 0, 0);
#else
  return __builtin_amdgcn_mfma_f32_16x16x16bf16_1k(
      __builtin_bit_cast(short4_, a), __builtin_bit_cast(short4_, b), c, 0, 0, 0);
#endif
}

__device__ __forceinline__ bf16x4 lo4(bf16x8 v) {
  return __builtin_shufflevector(v, v, 0, 1, 2, 3);
}
__device__ __forceinline__ bf16x4 hi4(bf16x8 v) {
  return __builtin_shufflevector(v, v, 4, 5, 6, 7);
}

// --------------------------- prep: weight transposes + x convert (one launch)
struct PrepArgs { const float* w[4]; bf16* wt[4]; const float* x; bf16* xb; };

__global__ __launch_bounds__(256)
void prep(PrepArgs p) {
  const int bid = blockIdx.x;
  if (bid < 4096) {
    __shared__ float tile[32][33];
    const int z = bid >> 10, xy = bid & 1023;
    const int bx = xy & 31, by = xy >> 5;
    const float* in = p.w[z];
    bf16* out = p.wt[z];
    int tx = threadIdx.x & 31, ty = threadIdx.x >> 5;
    int n0 = bx * 32, k0 = by * 32;
#pragma unroll
    for (int j = 0; j < 32; j += 8)
      tile[ty + j][tx] = in[(size_t)(k0 + ty + j) * C_ + n0 + tx];
    __syncthreads();
#pragma unroll
    for (int j = 0; j < 32; j += 8)
      out[(size_t)(n0 + ty + j) * C_ + k0 + tx] = (bf16)tile[tx][ty + j];
  } else {
    int i = ((bid - 4096) * 256 + threadIdx.x) * 8;
    float4 a = *(const float4*)(p.x + i);
    float4 b = *(const float4*)(p.x + i + 4);
    bf16x8 o;
    o[0] = (bf16)a.x; o[1] = (bf16)a.y; o[2] = (bf16)a.z; o[3] = (bf16)a.w;
    o[4] = (bf16)b.x; o[5] = (bf16)b.y; o[6] = (bf16)b.z; o[7] = (bf16)b.w;
    *(bf16x8*)(p.xb + i) = o;
  }
}

// ---------------------------------------------------------------- QKV GEMM
struct GQ {
  const bf16* A; const bf16* Bt;
  const float* bias[3];
  bf16* Cout; bf16* vt; int N; int K;
};

__global__ __launch_bounds__(256, 2)
void gemm128(GQ g) {
  __shared__ __align__(16) bf16 As[128 * 64];
  __shared__ __align__(16) bf16 Bs[128 * 64];
  const int tid = threadIdx.x;
  const int wave = tid >> 6, lane = tid & 63;
  const int quad = lane >> 4, l16 = lane & 15;
  const int m0 = blockIdx.y * 128, n0 = blockIdx.x * 128;
  const int wm = (wave >> 1) * 64, wn = (wave & 1) * 64;

  floatx4 acc[4][4] = {};

  int rA[4], cA[4];
#pragma unroll
  for (int t = 0; t < 4; ++t) {
    int pch = (wave * 4 + t) * 64 + lane;
    rA[t] = pch >> 3;
    cA[t] = (pch & 7) ^ (rA[t] & 7);
  }

  for (int k0 = 0; k0 < g.K; k0 += 64) {
    __syncthreads();
#pragma unroll
    for (int t = 0; t < 4; ++t) {
      load_lds16(g.A + (size_t)(m0 + rA[t]) * g.K + k0 + cA[t] * 8,
                 As + (wave * 4 + t) * 512);
      load_lds16(g.Bt + (size_t)(n0 + rA[t]) * g.K + k0 + cA[t] * 8,
                 Bs + (wave * 4 + t) * 512);
    }
    __builtin_amdgcn_s_waitcnt(0x0f70);
    __syncthreads();
#pragma unroll
    for (int s = 0; s < 2; ++s) {
      bf16x8 af[4], bfr[4];
#pragma unroll
      for (int i = 0; i < 4; ++i) {
        int mr = wm + i * 16 + l16;
        af[i] = *(const bf16x8*)(As + ((mr * 8) + ((s * 4 + quad) ^ (mr & 7))) * 8);
        int nr = wn + i * 16 + l16;
        bfr[i] = *(const bf16x8*)(Bs + ((nr * 8) + ((s * 4 + quad) ^ (nr & 7))) * 8);
      }
#pragma unroll
      for (int i = 0; i < 4; ++i)
#pragma unroll
        for (int j = 0; j < 4; ++j)
          acc[i][j] = __builtin_amdgcn_mfma_f32_16x16x32_bf16(af[i], bfr[j],
                                                              acc[i][j], 0, 0, 0);
    }
  }

  const bool vsplit = (n0 >= 2048);
#pragma unroll
  for (int j = 0; j < 4; ++j) {
    int col = n0 + wn + j * 16 + l16;
    const float* bp = g.bias[col >> 10];
    float bv = bp[col & 1023];
    if (vsplit) {
      int cv = col - 2048;  // cv = h*64 + d
      // token layout permuted within each 32-group: t' = q4*8 + kt*4 + j
      // (so attn can read both kt fragments of V^T with ONE b128 LDS read).
      bf16* dstb = g.vt + ((size_t)((m0 >> 11) * 16 + (cv >> 6)) * 64 + (cv & 63)) * (size_t)T_
                   + (m0 & 2047) + wm + quad * 8;
#pragma unroll
      for (int i = 0; i < 4; ++i) {
        bf16x4 pk;
#pragma unroll
        for (int r = 0; r < 4; ++r) pk[r] = (bf16)(acc[i][j][r] + bv);
        *(bf16x4*)(dstb + (i >> 1) * 32 + (i & 1) * 4) = pk;
      }
    } else {
#pragma unroll
      for (int i = 0; i < 4; ++i) {
#pragma unroll
        for (int r = 0; r < 4; ++r) {
          int row = m0 + wm + i * 16 + quad * 4 + r;
          g.Cout[(size_t)row * g.N + col] = (bf16)(acc[i][j][r] + bv);
        }
      }
    }
  }
}

// ---------------------------------------------------------------- out GEMM
__global__ __launch_bounds__(256, 2)
void gemm_out(const bf16* __restrict__ A, const bf16* __restrict__ Bt,
              const float* __restrict__ bias, float* __restrict__ C) {
  __shared__ __align__(16) bf16 As[64 * 64];
  __shared__ __align__(16) bf16 Bs[128 * 64];
  const int tid = threadIdx.x;
  const int wave = tid >> 6, lane = tid & 63;
  const int quad = lane >> 4, l16 = lane & 15;
  const int m0 = blockIdx.y * 64, n0 = blockIdx.x * 128;
  const int wm = (wave >> 1) * 32, wn = (wave & 1) * 64;

  floatx4 acc[2][4] = {};

  int rA[2], cA[2], rB[4], cB[4];
#pragma unroll
  for (int t = 0; t < 2; ++t) {
    int p = t * 256 + tid;
    rA[t] = p >> 3; cA[t] = (p & 7) ^ (rA[t] & 7);
  }
#pragma unroll
  for (int t = 0; t < 4; ++t) {
    int p = t * 256 + tid;
    rB[t] = p >> 3; cB[t] = (p & 7) ^ (rB[t] & 7);
  }

  for (int k0 = 0; k0 < 1024; k0 += 64) {
    __syncthreads();
#pragma unroll
    for (int t = 0; t < 2; ++t)
      load_lds16(A + (size_t)(m0 + rA[t]) * 1024 + k0 + cA[t] * 8,
                 As + t * 2048 + wave * 512);
#pragma unroll
    for (int t = 0; t < 4; ++t)
      load_lds16(Bt + (size_t)(n0 + rB[t]) * 1024 + k0 + cB[t] * 8,
                 Bs + t * 2048 + wave * 512);
    __builtin_amdgcn_s_waitcnt(0x0f70);
    __syncthreads();
#pragma unroll
    for (int s = 0; s < 2; ++s) {
      bf16x8 af[2], bfr[4];
#pragma unroll
      for (int i = 0; i < 2; ++i) {
        int mr = wm + i * 16 + l16;
        af[i] = *(const bf16x8*)(As + ((mr * 8) + ((s * 4 + quad) ^ (mr & 7))) * 8);
      }
#pragma unroll
      for (int j = 0; j < 4; ++j) {
        int nr = wn + j * 16 + l16;
        bfr[j] = *(const bf16x8*)(Bs + ((nr * 8) + ((s * 4 + quad) ^ (nr & 7))) * 8);
      }
#pragma unroll
      for (int i = 0; i < 2; ++i)
#pragma unroll
        for (int j = 0; j < 4; ++j)
          acc[i][j] = __builtin_amdgcn_mfma_f32_16x16x32_bf16(af[i], bfr[j],
                                                              acc[i][j], 0, 0, 0);
    }
  }

#pragma unroll
  for (int j = 0; j < 4; ++j) {
    int col = n0 + wn + j * 16 + l16;
    float bv = bias[col];
#pragma unroll
    for (int i = 0; i < 2; ++i)
#pragma unroll
      for (int r = 0; r < 4; ++r) {
        int row = m0 + wm + i * 16 + quad * 4 + r;
        C[(size_t)row * 1024 + col] = acc[i][j][r] + bv;
      }
  }
}

// ---------------------------------------------------------------- attention
// Fixed-max streaming softmax; 512 threads = 4 q-strips x 2 k-halves;
// in-register P (swapped QK, mfma16 PV); additive k-partials; LPT remap.
// R4: (a) V staged in a kt-interleaved token layout so each V fragment pair
// is ONE conflict-free b128 read (was 8x b64 with 4-way conflicts: 2.2M
// SQ_LDS_BANK_CONFLICT); (b) KVBLK=128 — two 64-tiles per vmcnt(0)+barrier
// round (halves sync overhead, same staging volume); (c) s_setprio(1)
// around the compute cluster.
__constant__ int yy_map[24] = {7, 8, 16, 9, 17, 6, 10, 18, 11, 19, 5, 12,
                               20, 13, 21, 4, 14, 22, 15, 23, 3, 2, 1, 0};

__global__ __launch_bounds__(512, 2)
void attn8(const bf16* __restrict__ qk, const bf16* __restrict__ vt,
           bf16* __restrict__ y, bf16* __restrict__ po, float* __restrict__ pl) {
  // carve: K[2buf][2sub][64*64] at [0,16384) | V same at [16384,32768)
  // end-combine reuses front 34816 B as float scratch.
  __shared__ __align__(16) bf16 smem[32768];
  const int tid = threadIdx.x, wave = tid >> 6, lane = tid & 63;
  const int quad = lane >> 4, l16 = lane & 15;
  const int qs = wave >> 1, kh = wave & 1;
  const int bh = blockIdx.x, b = bh >> 4, h = bh & 15;
  const int yy = yy_map[blockIdx.y];
  int qb, kbeg, kcnt, seg;
  if (yy < 8)       { qb = yy;      kbeg = 0;      kcnt = 2 * qb + 2; seg = -1; }
  else if (yy < 16) { qb = 23 - yy; kbeg = 0;      kcnt = qb + 1;     seg = 0;  }
  else              { qb = 31 - yy; kbeg = qb + 1; kcnt = qb + 1;     seg = 1;  }

  const float L2E = 1.4426950408889634f;
  const float slope2 = exp2f(-0.5f * (float)(h + 1)) * L2E;  // log2-domain slope
  const float scl2 = 0.125f * L2E;
  const float M0 = 14.0f;  // fixed softmax max (log2 units); scores << 14

  // staging: 512 threads, 1 chunk per 64-tile per tensor
  const int rS = tid >> 3;
  const int cS = (tid & 7) ^ (rS & 7);
  const bf16* kbase = qk + (size_t)b * T_ * QK_LD + 1024 + h * 64;
  const bf16* vbase = vt + (size_t)bh * 64 * T_;

  const int q0 = qb * 128;
  const int w0 = q0 + qs * 32;

  bf16x8 qf[2][2];
#pragma unroll
  for (int qt = 0; qt < 2; ++qt)
#pragma unroll
    for (int s = 0; s < 2; ++s)
      qf[qt][s] = *(const bf16x8*)(qk +
          (size_t)(b * T_ + w0 + qt * 16 + l16) * QK_LD + h * 64 + s * 32 + quad * 8);

  // per-lane softmax constants (q lives on l16; k on quad*4+r (+16kt))
  const int qi0 = w0 + l16;
  float qoff[2];
  qoff[0] = slope2 * (float)qi0 + M0;
  qoff[1] = qoff[0] + slope2 * 16.0f;
  float kc[2][4];
#pragma unroll
  for (int kt = 0; kt < 2; ++kt)
#pragma unroll
    for (int r = 0; r < 4; ++r)
      kc[kt][r] = slope2 * (float)(kt * 16 + quad * 4 + r);

  floatx4 o[2][4];
#pragma unroll
  for (int qt = 0; qt < 2; ++qt)
#pragma unroll
    for (int n = 0; n < 4; ++n) o[qt][n] = (floatx4)0.f;
  float lsum[2] = {0.f, 0.f};

  // prologue: stage tiles kbeg, kbeg+1 into buffer 0 (kcnt >= 2 always)
#pragma unroll
  for (int s2 = 0; s2 < 2; ++s2) {
    load_lds16(kbase + (size_t)((kbeg + s2) * 64 + rS) * QK_LD + cS * 8,
               smem + s2 * 4096 + wave * 512);
    load_lds16(vbase + (size_t)rS * T_ + (kbeg + s2) * 64 + cS * 8,
               smem + 16384 + s2 * 4096 + wave * 512);
  }
  __builtin_amdgcn_s_waitcnt(0x0f70);
  __syncthreads();

  const int nit = (kcnt + 1) >> 1;
  for (int it = 0; it < nit; ++it) {
    const int cur = it & 1;

    if (it + 1 < nit) {
      const int nt0 = kbeg + 2 * it + 2;
#pragma unroll
      for (int s2 = 0; s2 < 2; ++s2) {
        load_lds16(kbase + (size_t)((nt0 + s2) * 64 + rS) * QK_LD + cS * 8,
                   smem + (cur ^ 1) * 8192 + s2 * 4096 + wave * 512);
        load_lds16(vbase + (size_t)rS * T_ + (nt0 + s2) * 64 + cS * 8,
                   smem + 16384 + (cur ^ 1) * 8192 + s2 * 4096 + wave * 512);
      }
    }

#pragma unroll
    for (int sub = 0; sub < 2; ++sub) {
      const int tile = 2 * it + sub;
      if (tile < kcnt) {
        const int kj0 = (kbeg + tile) * 64;
        const bf16* Klc = smem + cur * 8192 + sub * 4096;
        const bf16* Vlc = smem + 16384 + cur * 8192 + sub * 4096;

        // K fragments (A-operand of swapped QK): K[kh*32+kt*16+l16][d]
        bf16x8 kf[2][2];
#pragma unroll
        for (int ss = 0; ss < 2; ++ss)
#pragma unroll
          for (int kt = 0; kt < 2; ++kt) {
            const int krow = kh * 32 + kt * 16 + l16;
            kf[ss][kt] = *(const bf16x8*)(Klc + krow * 64 +
                                          (((ss * 4 + quad) ^ (krow & 7)) * 8));
          }
        // V^T fragments: ONE b128 per nt covers both kt (kt-interleaved layout)
        bf16x8 vf8[4];
#pragma unroll
        for (int nt = 0; nt < 4; ++nt) {
          const int drow = nt * 16 + l16;
          vf8[nt] = *(const bf16x8*)(Vlc + drow * 64 +
                                     (((kh * 4 + quad) ^ (drow & 7)) * 8));
        }

        const int kbi = kj0 + kh * 32;
        const float kb = slope2 * (float)kbi;

        __builtin_amdgcn_s_setprio(1);
#pragma unroll
        for (int qt = 0; qt < 2; ++qt) {
          const int rb = w0 + qt * 16;
          floatx4 st[2] = {};
#pragma unroll
          for (int ss = 0; ss < 2; ++ss)
#pragma unroll
            for (int kt = 0; kt < 2; ++kt)
              st[kt] = __builtin_amdgcn_mfma_f32_16x16x32_bf16(kf[ss][kt], qf[qt][ss],
                                                               st[kt], 0, 0, 0);

          const float bb = kb - qoff[qt];
          const int qi = qi0 + qt * 16;
          bf16x4 pb[2];
          if (kbi + 31 > rb) {   // diagonal: mask k > q
#pragma unroll
            for (int kt = 0; kt < 2; ++kt) {
#pragma unroll
              for (int r = 0; r < 4; ++r) {
                float p = __builtin_amdgcn_exp2f(
                    fmaf(st[kt][r], scl2, bb + kc[kt][r]));
                if (kbi + kt * 16 + quad * 4 + r > qi) p = 0.f;
                lsum[qt] += p;
                pb[kt][r] = (bf16)p;
              }
            }
          } else {
#pragma unroll
            for (int kt = 0; kt < 2; ++kt) {
#pragma unroll
              for (int r = 0; r < 4; ++r) {
                float p = __builtin_amdgcn_exp2f(
                    fmaf(st[kt][r], scl2, bb + kc[kt][r]));
                lsum[qt] += p;
                pb[kt][r] = (bf16)p;
              }
            }
          }

          // PV: O^T[d][q] += V^T[d][k] * P^T[k][q]
#pragma unroll
          for (int nt = 0; nt < 4; ++nt) {
            o[qt][nt] = mfma16(lo4(vf8[nt]), pb[0], o[qt][nt]);
            o[qt][nt] = mfma16(hi4(vf8[nt]), pb[1], o[qt][nt]);
          }
        }
        __builtin_amdgcn_s_setprio(0);
      }
    }

    __builtin_amdgcn_s_waitcnt(0x0f70);  // vmcnt(0): next pair landed
    __syncthreads();
  }

  // cross-wave combine of the two k-halves (additive: fixed-max softmax)
  float* Cb = (float*)smem;  // 34816 B used; K/V dead now
  if (kh == 1) {
#pragma unroll
    for (int qt = 0; qt < 2; ++qt) {
#pragma unroll
      for (int n = 0; n < 4; ++n)
        *(floatx4*)(Cb + (((qs * 2 + qt) * 4 + n) * 64 + lane) * 4) = o[qt][n];
      Cb[8192 + (qs * 2 + qt) * 64 + lane] = lsum[qt];
    }
  }
  __syncthreads();
  if (kh == 1) return;
#pragma unroll
  for (int qt = 0; qt < 2; ++qt) {
#pragma unroll
    for (int n = 0; n < 4; ++n)
      o[qt][n] += *(const floatx4*)(Cb + (((qs * 2 + qt) * 4 + n) * 64 + lane) * 4);
    lsum[qt] += Cb[8192 + (qs * 2 + qt) * 64 + lane];
    lsum[qt] += __shfl_xor(lsum[qt], 16);
    lsum[qt] += __shfl_xor(lsum[qt], 32);   // full row-sum, replicated per l16
  }

  if (seg < 0) {
#pragma unroll
    for (int qt = 0; qt < 2; ++qt) {
      const float inv = 1.f / lsum[qt];
      bf16* yp = y + (size_t)(b * T_ + w0 + qt * 16 + l16) * C_ + h * 64 + quad * 4;
#pragma unroll
      for (int nt = 0; nt < 4; ++nt) {
        bf16x4 pk;
#pragma unroll
        for (int r = 0; r < 4; ++r) pk[r] = (bf16)(o[qt][nt][r] * inv);
        *(bf16x4*)(yp + nt * 16) = pk;
      }
    }
  } else {
    // packed partials: [chunk=qt*2+half][t256=qs*64+lane][8]
    const int pid = (bh * 8 + (qb - 8)) * 2 + seg;
    bf16* pob = po + (size_t)pid * 8192;
#pragma unroll
    for (int qt = 0; qt < 2; ++qt) {
#pragma unroll
      for (int half = 0; half < 2; ++half) {
        bf16x8 pk;
#pragma unroll
        for (int jj = 0; jj < 8; ++jj)
          pk[jj] = (bf16)o[qt][half * 2 + (jj >> 2)][jj & 3];
        *(bf16x8*)(pob + (qt * 2 + half) * 2048 + (qs * 64 + lane) * 8) = pk;
      }
      if (quad == 0)
        pl[pid * 128 + qs * 32 + qt * 16 + l16] = lsum[qt];
    }
  }
}

// --------------------------------------------------- combine split segments
__global__ __launch_bounds__(256)
void combine(const bf16* __restrict__ po, const float* __restrict__ pl,
             bf16* __restrict__ y) {
  const int x = blockIdx.x;
  const int bh = x >> 3, qb = (x & 7) + 8;
  const int b = bh >> 4, h = bh & 15;
  const int pid0 = (bh * 8 + (qb - 8)) * 2;
  const bf16* p0 = po + (size_t)pid0 * 8192;
  const bf16* p1 = p0 + 8192;
  const int t = threadIdx.x;
  const int qs = t >> 6, quad = (t >> 4) & 3, l16 = t & 15;

  float linv[2];
  int row[2];
#pragma unroll
  for (int qt = 0; qt < 2; ++qt) {
    row[qt] = qs * 32 + qt * 16 + l16;
    linv[qt] = 1.f / (pl[pid0 * 128 + row[qt]] + pl[(pid0 + 1) * 128 + row[qt]]);
  }

#pragma unroll
  for (int qt = 0; qt < 2; ++qt)
#pragma unroll
    for (int half = 0; half < 2; ++half) {
      bf16x8 a = *(const bf16x8*)(p0 + (qt * 2 + half) * 2048 + t * 8);
      bf16x8 c = *(const bf16x8*)(p1 + (qt * 2 + half) * 2048 + t * 8);
#pragma unroll
      for (int g = 0; g < 2; ++g) {
        bf16x4 outv;
#pragma unroll
        for (int r = 0; r < 4; ++r)
          outv[r] = (bf16)(((float)a[g * 4 + r] + (float)c[g * 4 + r]) * linv[qt]);
        const int col = (half * 2 + g) * 16 + quad * 4;
        *(bf16x4*)(y + (size_t)(b * T_ + qb * 128 + row[qt]) * C_ + h * 64 + col) = outv;
      }
    }
}

// ---------------------------------------------------------------- launch
extern "C" void kernel_launch(void* const* d_in, const int* in_sizes, int n_in,
                              void* d_out, int out_size, void* d_ws, size_t ws_size,
                              hipStream_t stream) {
  const float* x  = (const float*)d_in[0];
  const float* Wq = (const float*)d_in[1];
  const float* bq = (const float*)d_in[2];
  const float* Wk = (const float*)d_in[3];
  const float* bk = (const float*)d_in[4];
  const float* Wv = (const float*)d_in[5];
  const float* bv = (const float*)d_in[6];
  const float* Wo = (const float*)d_in[7];
  const float* bo = (const float*)d_in[8];

  bf16* ws  = (bf16*)d_ws;
  bf16* WtQ = ws;
  bf16* WtK = WtQ + (size_t)C_ * C_;
  bf16* WtV = WtK + (size_t)C_ * C_;
  bf16* WtO = WtV + (size_t)C_ * C_;
  bf16* xb  = WtO + (size_t)C_ * C_;           // [4096][1024]
  bf16* qkb = xb + (size_t)M_ * C_;            // [4096][2048]  (Q | K)
  bf16* vtb = qkb + (size_t)M_ * 2 * C_;       // [32][64][2048] (kt-interleaved)
  bf16* yb  = vtb + (size_t)M_ * C_;           // [4096][1024]
  bf16* pob = yb + (size_t)M_ * C_;            // [512][8192] packed partial O
  float* plb = (float*)(pob + (size_t)512 * 8192);

  PrepArgs pp;
  pp.w[0] = Wq; pp.w[1] = Wk; pp.w[2] = Wv; pp.w[3] = Wo;
  pp.wt[0] = WtQ; pp.wt[1] = WtK; pp.wt[2] = WtV; pp.wt[3] = WtO;
  pp.x = x; pp.xb = xb;
  prep<<<dim3(4096 + M_ * C_ / (256 * 8)), 256, 0, stream>>>(pp);

  GQ gq;
  gq.A = xb; gq.Bt = WtQ;
  gq.bias[0] = bq; gq.bias[1] = bk; gq.bias[2] = bv;
  gq.Cout = qkb; gq.vt = vtb; gq.N = 2 * C_; gq.K = C_;
  gemm128<<<dim3(24, 32), 256, 0, stream>>>(gq);

  attn8<<<dim3(32, 24), 512, 0, stream>>>(qkb, vtb, yb, pob, plb);
  combine<<<dim3(32 * 8), 256, 0, stream>>>(pob, plb, yb);

  gemm_out<<<dim3(8, 64), 256, 0, stream>>>(yb, WtO, bo, (float*)d_out);
}

// Round 5
// 175.061 us; speedup vs baseline: 1.0435x; 1.0435x over previous
//
#include <hip/hip_runtime.h>
#include <hip/hip_bf16.h>

typedef __bf16 bf16;
typedef __bf16 bf16x4 __attribute__((ext_vector_type(4)));
typedef __bf16 bf16x8 __attribute__((ext_vector_type(8)));
typedef float floatx4 __attribute__((ext_vector_type(4)));
typedef short short4_ __attribute__((ext_vector_type(4)));

#define B_ 2
#define T_ 2048
#define C_ 1024
#define H_ 16
#define D_ 64
#define M_ 4096
#define QK_LD 2048

__device__ __forceinline__ void load_lds16(const void* g, void* l) {
  __builtin_amdgcn_global_load_lds(
      (const __attribute__((address_space(1))) unsigned int*)g,
      (__attribute__((address_space(3))) unsigned int*)l, 16, 0, 0);
}

// 16x16x16 bf16 MFMA: A[m=l16][k=quad*4+j], B[k=quad*4+j][n=l16] — the B
// layout matches the C/D layout of a swapped QK^T (in-register softmax->PV).
__device__ __forceinline__ floatx4 mfma16(bf16x4 a, bf16x4 b, floatx4 c) {
#if __has_builtin(__builtin_amdgcn_mfma_f32_16x16x16_bf16)
  return __builtin_amdgcn_mfma_f32_16x16x16_bf16(a, b, c, 0, 0, 0);
#else
  return __builtin_amdgcn_mfma_f32_16x16x16bf16_1k(
      __builtin_bit_cast(short4_, a), __builtin_bit_cast(short4_, b), c, 0, 0, 0);
#endif
}

__device__ __forceinline__ bf16x4 lo4(bf16x8 v) {
  return __builtin_shufflevector(v, v, 0, 1, 2, 3);
}
__device__ __forceinline__ bf16x4 hi4(bf16x8 v) {
  return __builtin_shufflevector(v, v, 4, 5, 6, 7);
}

// --------------------------- prep: weight transposes + x convert (one launch)
struct PrepArgs { const float* w[4]; bf16* wt[4]; const float* x; bf16* xb; };

__global__ __launch_bounds__(256)
void prep(PrepArgs p) {
  const int bid = blockIdx.x;
  if (bid < 4096) {
    __shared__ float tile[32][33];
    const int z = bid >> 10, xy = bid & 1023;
    const int bx = xy & 31, by = xy >> 5;
    const float* in = p.w[z];
    bf16* out = p.wt[z];
    int tx = threadIdx.x & 31, ty = threadIdx.x >> 5;
    int n0 = bx * 32, k0 = by * 32;
#pragma unroll
    for (int j = 0; j < 32; j += 8)
      tile[ty + j][tx] = in[(size_t)(k0 + ty + j) * C_ + n0 + tx];
    __syncthreads();
#pragma unroll
    for (int j = 0; j < 32; j += 8)
      out[(size_t)(n0 + ty + j) * C_ + k0 + tx] = (bf16)tile[tx][ty + j];
  } else {
    int i = ((bid - 4096) * 256 + threadIdx.x) * 8;
    float4 a = *(const float4*)(p.x + i);
    float4 b = *(const float4*)(p.x + i + 4);
    bf16x8 o;
    o[0] = (bf16)a.x; o[1] = (bf16)a.y; o[2] = (bf16)a.z; o[3] = (bf16)a.w;
    o[4] = (bf16)b.x; o[5] = (bf16)b.y; o[6] = (bf16)b.z; o[7] = (bf16)b.w;
    *(bf16x8*)(p.xb + i) = o;
  }
}

// ---------------------------------------------------------------- QKV GEMM
struct GQ {
  const bf16* A; const bf16* Bt;
  const float* bias[3];
  bf16* Cout; bf16* vt; int N; int K;
};

__global__ __launch_bounds__(256, 2)
void gemm128(GQ g) {
  __shared__ __align__(16) bf16 As[128 * 64];
  __shared__ __align__(16) bf16 Bs[128 * 64];
  const int tid = threadIdx.x;
  const int wave = tid >> 6, lane = tid & 63;
  const int quad = lane >> 4, l16 = lane & 15;
  const int m0 = blockIdx.y * 128, n0 = blockIdx.x * 128;
  const int wm = (wave >> 1) * 64, wn = (wave & 1) * 64;

  floatx4 acc[4][4] = {};

  int rA[4], cA[4];
#pragma unroll
  for (int t = 0; t < 4; ++t) {
    int pch = (wave * 4 + t) * 64 + lane;
    rA[t] = pch >> 3;
    cA[t] = (pch & 7) ^ (rA[t] & 7);
  }

  for (int k0 = 0; k0 < g.K; k0 += 64) {
    __syncthreads();
#pragma unroll
    for (int t = 0; t < 4; ++t) {
      load_lds16(g.A + (size_t)(m0 + rA[t]) * g.K + k0 + cA[t] * 8,
                 As + (wave * 4 + t) * 512);
      load_lds16(g.Bt + (size_t)(n0 + rA[t]) * g.K + k0 + cA[t] * 8,
                 Bs + (wave * 4 + t) * 512);
    }
    __builtin_amdgcn_s_waitcnt(0x0f70);
    __syncthreads();
#pragma unroll
    for (int s = 0; s < 2; ++s) {
      bf16x8 af[4], bfr[4];
#pragma unroll
      for (int i = 0; i < 4; ++i) {
        int mr = wm + i * 16 + l16;
        af[i] = *(const bf16x8*)(As + ((mr * 8) + ((s * 4 + quad) ^ (mr & 7))) * 8);
        int nr = wn + i * 16 + l16;
        bfr[i] = *(const bf16x8*)(Bs + ((nr * 8) + ((s * 4 + quad) ^ (nr & 7))) * 8);
      }
#pragma unroll
      for (int i = 0; i < 4; ++i)
#pragma unroll
        for (int j = 0; j < 4; ++j)
          acc[i][j] = __builtin_amdgcn_mfma_f32_16x16x32_bf16(af[i], bfr[j],
                                                              acc[i][j], 0, 0, 0);
    }
  }

  const bool vsplit = (n0 >= 2048);
#pragma unroll
  for (int j = 0; j < 4; ++j) {
    int col = n0 + wn + j * 16 + l16;
    const float* bp = g.bias[col >> 10];
    float bv = bp[col & 1023];
    if (vsplit) {
      int cv = col - 2048;  // cv = h*64 + d
      // token layout permuted within each 32-group: t' = q4*8 + kt*4 + j
      // (so attn reads both kt fragments of V^T with ONE b128 LDS read).
      bf16* dstb = g.vt + ((size_t)((m0 >> 11) * 16 + (cv >> 6)) * 64 + (cv & 63)) * (size_t)T_
                   + (m0 & 2047) + wm + quad * 8;
#pragma unroll
      for (int ii = 0; ii < 2; ++ii) {
        bf16x8 pk;
#pragma unroll
        for (int r = 0; r < 8; ++r)
          pk[r] = (bf16)(acc[ii * 2 + (r >> 2)][j][r & 3] + bv);
        *(bf16x8*)(dstb + ii * 32) = pk;
      }
    } else {
#pragma unroll
      for (int i = 0; i < 4; ++i) {
#pragma unroll
        for (int r = 0; r < 4; ++r) {
          int row = m0 + wm + i * 16 + quad * 4 + r;
          g.Cout[(size_t)row * g.N + col] = (bf16)(acc[i][j][r] + bv);
        }
      }
    }
  }
}

// ---------------------------------------------------------------- out GEMM
__global__ __launch_bounds__(256, 2)
void gemm_out(const bf16* __restrict__ A, const bf16* __restrict__ Bt,
              const float* __restrict__ bias, float* __restrict__ C) {
  __shared__ __align__(16) bf16 As[64 * 64];
  __shared__ __align__(16) bf16 Bs[128 * 64];
  const int tid = threadIdx.x;
  const int wave = tid >> 6, lane = tid & 63;
  const int quad = lane >> 4, l16 = lane & 15;
  const int m0 = blockIdx.y * 64, n0 = blockIdx.x * 128;
  const int wm = (wave >> 1) * 32, wn = (wave & 1) * 64;

  floatx4 acc[2][4] = {};

  int rA[2], cA[2], rB[4], cB[4];
#pragma unroll
  for (int t = 0; t < 2; ++t) {
    int p = t * 256 + tid;
    rA[t] = p >> 3; cA[t] = (p & 7) ^ (rA[t] & 7);
  }
#pragma unroll
  for (int t = 0; t < 4; ++t) {
    int p = t * 256 + tid;
    rB[t] = p >> 3; cB[t] = (p & 7) ^ (rB[t] & 7);
  }

  for (int k0 = 0; k0 < 1024; k0 += 64) {
    __syncthreads();
#pragma unroll
    for (int t = 0; t < 2; ++t)
      load_lds16(A + (size_t)(m0 + rA[t]) * 1024 + k0 + cA[t] * 8,
                 As + t * 2048 + wave * 512);
#pragma unroll
    for (int t = 0; t < 4; ++t)
      load_lds16(Bt + (size_t)(n0 + rB[t]) * 1024 + k0 + cB[t] * 8,
                 Bs + t * 2048 + wave * 512);
    __builtin_amdgcn_s_waitcnt(0x0f70);
    __syncthreads();
#pragma unroll
    for (int s = 0; s < 2; ++s) {
      bf16x8 af[2], bfr[4];
#pragma unroll
      for (int i = 0; i < 2; ++i) {
        int mr = wm + i * 16 + l16;
        af[i] = *(const bf16x8*)(As + ((mr * 8) + ((s * 4 + quad) ^ (mr & 7))) * 8);
      }
#pragma unroll
      for (int j = 0; j < 4; ++j) {
        int nr = wn + j * 16 + l16;
        bfr[j] = *(const bf16x8*)(Bs + ((nr * 8) + ((s * 4 + quad) ^ (nr & 7))) * 8);
      }
#pragma unroll
      for (int i = 0; i < 2; ++i)
#pragma unroll
        for (int j = 0; j < 4; ++j)
          acc[i][j] = __builtin_amdgcn_mfma_f32_16x16x32_bf16(af[i], bfr[j],
                                                              acc[i][j], 0, 0, 0);
    }
  }

#pragma unroll
  for (int j = 0; j < 4; ++j) {
    int col = n0 + wn + j * 16 + l16;
    float bv = bias[col];
#pragma unroll
    for (int i = 0; i < 2; ++i)
#pragma unroll
      for (int r = 0; r < 4; ++r) {
        int row = m0 + wm + i * 16 + quad * 4 + r;
        C[(size_t)row * 1024 + col] = acc[i][j][r] + bv;
      }
  }
}

// ---------------------------------------------------------------- attention
// Fixed-max streaming softmax; 512 threads = 4 q-strips x 2 k-halves;
// in-register P (swapped QK, mfma16 PV); additive k-partials; LPT remap.
// R5: (a) branch-free pair body (odd tail tile moved to epilogue) — the
// runtime `if (tile<kcnt)` guard was blocking LLVM from interleaving the
// two independent sub-tile dependency chains (44.4us = 1567 cyc/wave-tile
// vs ~300 issue cyc: serial-chain-bound, occupancy capped at 4 waves/SIMD
// by VGPR 76>64); (b) XCD-aware 1-D grid: each XCD owns 4 bh, so its 4MB
// L2 holds those heads' K/V+Q (~3MB) — staging becomes local-L2 hits.
__constant__ int yy_map[24] = {7, 8, 16, 9, 17, 6, 10, 18, 11, 19, 5, 12,
                               20, 13, 21, 4, 14, 22, 15, 23, 3, 2, 1, 0};

__global__ __launch_bounds__(512, 2)
void attn8(const bf16* __restrict__ qk, const bf16* __restrict__ vt,
           bf16* __restrict__ y, bf16* __restrict__ po, float* __restrict__ pl) {
  // carve: K[2buf][2sub][64*64] at [0,16384) | V same at [16384,32768)
  // end-combine reuses front 34816 B as float scratch.
  __shared__ __align__(16) bf16 smem[32768];
  const int tid = threadIdx.x, wave = tid >> 6, lane = tid & 63;
  const int quad = lane >> 4, l16 = lane & 15;
  const int qs = wave >> 1, kh = wave & 1;
  // XCD-grouped decode: xcd = id&7 owns bh in [xcd*4, xcd*4+4); LPT on yy.
  const int id = blockIdx.x;
  const int pos = id >> 3;
  const int bh = (id & 7) * 4 + (pos & 3);
  const int b = bh >> 4, h = bh & 15;
  const int yy = yy_map[pos >> 2];
  int qb, kbeg, kcnt, seg;
  if (yy < 8)       { qb = yy;      kbeg = 0;      kcnt = 2 * qb + 2; seg = -1; }
  else if (yy < 16) { qb = 23 - yy; kbeg = 0;      kcnt = qb + 1;     seg = 0;  }
  else              { qb = 31 - yy; kbeg = qb + 1; kcnt = qb + 1;     seg = 1;  }

  const float L2E = 1.4426950408889634f;
  const float slope2 = exp2f(-0.5f * (float)(h + 1)) * L2E;  // log2-domain slope
  const float scl2 = 0.125f * L2E;
  const float M0 = 14.0f;  // fixed softmax max (log2 units); scores << 14

  // staging: 512 threads, 1 chunk per 64-tile per tensor
  const int rS = tid >> 3;
  const int cS = (tid & 7) ^ (rS & 7);
  const bf16* kbase = qk + (size_t)b * T_ * QK_LD + 1024 + h * 64;
  const bf16* vbase = vt + (size_t)bh * 64 * T_;

  const int q0 = qb * 128;
  const int w0 = q0 + qs * 32;

  bf16x8 qf[2][2];
#pragma unroll
  for (int qt = 0; qt < 2; ++qt)
#pragma unroll
    for (int s = 0; s < 2; ++s)
      qf[qt][s] = *(const bf16x8*)(qk +
          (size_t)(b * T_ + w0 + qt * 16 + l16) * QK_LD + h * 64 + s * 32 + quad * 8);

  // per-lane softmax constants (q lives on l16; k on quad*4+r (+16kt))
  const int qi0 = w0 + l16;
  float qoff[2];
  qoff[0] = slope2 * (float)qi0 + M0;
  qoff[1] = qoff[0] + slope2 * 16.0f;
  float kc[2][4];
#pragma unroll
  for (int kt = 0; kt < 2; ++kt)
#pragma unroll
    for (int r = 0; r < 4; ++r)
      kc[kt][r] = slope2 * (float)(kt * 16 + quad * 4 + r);

  floatx4 o[2][4];
#pragma unroll
  for (int qt = 0; qt < 2; ++qt)
#pragma unroll
    for (int n = 0; n < 4; ++n) o[qt][n] = (floatx4)0.f;
  float lsum[2] = {0.f, 0.f};

  // one 64-k tile: reads from Klc/Vlc, updates o/lsum
  auto tilebody = [&](const bf16* Klc, const bf16* Vlc, int tile) {
    const int kj0 = (kbeg + tile) * 64;
    bf16x8 kf[2][2];
#pragma unroll
    for (int ss = 0; ss < 2; ++ss)
#pragma unroll
      for (int kt = 0; kt < 2; ++kt) {
        const int krow = kh * 32 + kt * 16 + l16;
        kf[ss][kt] = *(const bf16x8*)(Klc + krow * 64 +
                                      (((ss * 4 + quad) ^ (krow & 7)) * 8));
      }
    bf16x8 vf8[4];
#pragma unroll
    for (int nt = 0; nt < 4; ++nt) {
      const int drow = nt * 16 + l16;
      vf8[nt] = *(const bf16x8*)(Vlc + drow * 64 +
                                 (((kh * 4 + quad) ^ (drow & 7)) * 8));
    }

    const int kbi = kj0 + kh * 32;
    const float kb = slope2 * (float)kbi;

    __builtin_amdgcn_s_setprio(1);
#pragma unroll
    for (int qt = 0; qt < 2; ++qt) {
      const int rb = w0 + qt * 16;
      floatx4 st[2] = {};
#pragma unroll
      for (int ss = 0; ss < 2; ++ss)
#pragma unroll
        for (int kt = 0; kt < 2; ++kt)
          st[kt] = __builtin_amdgcn_mfma_f32_16x16x32_bf16(kf[ss][kt], qf[qt][ss],
                                                           st[kt], 0, 0, 0);

      const float bb = kb - qoff[qt];
      const int qi = qi0 + qt * 16;
      bf16x4 pb[2];
      if (kbi + 31 > rb) {   // diagonal: mask k > q (wave-uniform branch)
#pragma unroll
        for (int kt = 0; kt < 2; ++kt) {
#pragma unroll
          for (int r = 0; r < 4; ++r) {
            float p = __builtin_amdgcn_exp2f(
                fmaf(st[kt][r], scl2, bb + kc[kt][r]));
            if (kbi + kt * 16 + quad * 4 + r > qi) p = 0.f;
            lsum[qt] += p;
            pb[kt][r] = (bf16)p;
          }
        }
      } else {
#pragma unroll
        for (int kt = 0; kt < 2; ++kt) {
#pragma unroll
          for (int r = 0; r < 4; ++r) {
            float p = __builtin_amdgcn_exp2f(
                fmaf(st[kt][r], scl2, bb + kc[kt][r]));
            lsum[qt] += p;
            pb[kt][r] = (bf16)p;
          }
        }
      }

      // PV: O^T[d][q] += V^T[d][k] * P^T[k][q]
#pragma unroll
      for (int nt = 0; nt < 4; ++nt) {
        o[qt][nt] = mfma16(lo4(vf8[nt]), pb[0], o[qt][nt]);
        o[qt][nt] = mfma16(hi4(vf8[nt]), pb[1], o[qt][nt]);
      }
    }
    __builtin_amdgcn_s_setprio(0);
  };

  // prologue: stage tiles kbeg, kbeg+1 into buffer 0 (kcnt >= 2 always)
#pragma unroll
  for (int s2 = 0; s2 < 2; ++s2) {
    load_lds16(kbase + (size_t)((kbeg + s2) * 64 + rS) * QK_LD + cS * 8,
               smem + s2 * 4096 + wave * 512);
    load_lds16(vbase + (size_t)rS * T_ + (kbeg + s2) * 64 + cS * 8,
               smem + 16384 + s2 * 4096 + wave * 512);
  }
  __builtin_amdgcn_s_waitcnt(0x0f70);
  __syncthreads();

  const int npair = kcnt >> 1;
  const int nit = (kcnt + 1) >> 1;
  for (int it = 0; it < npair; ++it) {
    const int cur = it & 1;

    if (it + 1 < nit) {
      const int nt0 = kbeg + 2 * it + 2;
#pragma unroll
      for (int s2 = 0; s2 < 2; ++s2) {
        load_lds16(kbase + (size_t)((nt0 + s2) * 64 + rS) * QK_LD + cS * 8,
                   smem + (cur ^ 1) * 8192 + s2 * 4096 + wave * 512);
        load_lds16(vbase + (size_t)rS * T_ + (nt0 + s2) * 64 + cS * 8,
                   smem + 16384 + (cur ^ 1) * 8192 + s2 * 4096 + wave * 512);
      }
    }

    // both sub-tiles branch-free: LLVM may interleave the two chains
    tilebody(smem + cur * 8192,        smem + 16384 + cur * 8192,        2 * it);
    tilebody(smem + cur * 8192 + 4096, smem + 16384 + cur * 8192 + 4096, 2 * it + 1);

    __builtin_amdgcn_s_waitcnt(0x0f70);  // vmcnt(0): next pair landed
    __syncthreads();
  }
  if (kcnt & 1) {  // odd tail tile (staged by the last prefetch)
    const int cur = npair & 1;
    tilebody(smem + cur * 8192, smem + 16384 + cur * 8192, kcnt - 1);
    __syncthreads();  // all waves done reading K/V before Cb overwrite
  }

  // cross-wave combine of the two k-halves (additive: fixed-max softmax)
  float* Cb = (float*)smem;  // 34816 B used; K/V dead now
  if (kh == 1) {
#pragma unroll
    for (int qt = 0; qt < 2; ++qt) {
#pragma unroll
      for (int n = 0; n < 4; ++n)
        *(floatx4*)(Cb + (((qs * 2 + qt) * 4 + n) * 64 + lane) * 4) = o[qt][n];
      Cb[8192 + (qs * 2 + qt) * 64 + lane] = lsum[qt];
    }
  }
  __syncthreads();
  if (kh == 1) return;
#pragma unroll
  for (int qt = 0; qt < 2; ++qt) {
#pragma unroll
    for (int n = 0; n < 4; ++n)
      o[qt][n] += *(const floatx4*)(Cb + (((qs * 2 + qt) * 4 + n) * 64 + lane) * 4);
    lsum[qt] += Cb[8192 + (qs * 2 + qt) * 64 + lane];
    lsum[qt] += __shfl_xor(lsum[qt], 16);
    lsum[qt] += __shfl_xor(lsum[qt], 32);   // full row-sum, replicated per l16
  }

  if (seg < 0) {
#pragma unroll
    for (int qt = 0; qt < 2; ++qt) {
      const float inv = 1.f / lsum[qt];
      bf16* yp = y + (size_t)(b * T_ + w0 + qt * 16 + l16) * C_ + h * 64 + quad * 4;
#pragma unroll
      for (int nt = 0; nt < 4; ++nt) {
        bf16x4 pk;
#pragma unroll
        for (int r = 0; r < 4; ++r) pk[r] = (bf16)(o[qt][nt][r] * inv);
        *(bf16x4*)(yp + nt * 16) = pk;
      }
    }
  } else {
    // packed partials: [chunk=qt*2+half][t256=qs*64+lane][8]
    const int pid = (bh * 8 + (qb - 8)) * 2 + seg;
    bf16* pob = po + (size_t)pid * 8192;
#pragma unroll
    for (int qt = 0; qt < 2; ++qt) {
#pragma unroll
      for (int half = 0; half < 2; ++half) {
        bf16x8 pk;
#pragma unroll
        for (int jj = 0; jj < 8; ++jj)
          pk[jj] = (bf16)o[qt][half * 2 + (jj >> 2)][jj & 3];
        *(bf16x8*)(pob + (qt * 2 + half) * 2048 + (qs * 64 + lane) * 8) = pk;
      }
      if (quad == 0)
        pl[pid * 128 + qs * 32 + qt * 16 + l16] = lsum[qt];
    }
  }
}

// --------------------------------------------------- combine split segments
__global__ __launch_bounds__(256)
void combine(const bf16* __restrict__ po, const float* __restrict__ pl,
             bf16* __restrict__ y) {
  const int x = blockIdx.x;
  const int bh = x >> 3, qb = (x & 7) + 8;
  const int b = bh >> 4, h = bh & 15;
  const int pid0 = (bh * 8 + (qb - 8)) * 2;
  const bf16* p0 = po + (size_t)pid0 * 8192;
  const bf16* p1 = p0 + 8192;
  const int t = threadIdx.x;
  const int qs = t >> 6, quad = (t >> 4) & 3, l16 = t & 15;

  float linv[2];
  int row[2];
#pragma unroll
  for (int qt = 0; qt < 2; ++qt) {
    row[qt] = qs * 32 + qt * 16 + l16;
    linv[qt] = 1.f / (pl[pid0 * 128 + row[qt]] + pl[(pid0 + 1) * 128 + row[qt]]);
  }

#pragma unroll
  for (int qt = 0; qt < 2; ++qt)
#pragma unroll
    for (int half = 0; half < 2; ++half) {
      bf16x8 a = *(const bf16x8*)(p0 + (qt * 2 + half) * 2048 + t * 8);
      bf16x8 c = *(const bf16x8*)(p1 + (qt * 2 + half) * 2048 + t * 8);
#pragma unroll
      for (int g = 0; g < 2; ++g) {
        bf16x4 outv;
#pragma unroll
        for (int r = 0; r < 4; ++r)
          outv[r] = (bf16)(((float)a[g * 4 + r] + (float)c[g * 4 + r]) * linv[qt]);
        const int col = (half * 2 + g) * 16 + quad * 4;
        *(bf16x4*)(y + (size_t)(b * T_ + qb * 128 + row[qt]) * C_ + h * 64 + col) = outv;
      }
    }
}

// ---------------------------------------------------------------- launch
extern "C" void kernel_launch(void* const* d_in, const int* in_sizes, int n_in,
                              void* d_out, int out_size, void* d_ws, size_t ws_size,
                              hipStream_t stream) {
  const float* x  = (const float*)d_in[0];
  const float* Wq = (const float*)d_in[1];
  const float* bq = (const float*)d_in[2];
  const float* Wk = (const float*)d_in[3];
  const float* bk = (const float*)d_in[4];
  const float* Wv = (const float*)d_in[5];
  const float* bv = (const float*)d_in[6];
  const float* Wo = (const float*)d_in[7];
  const float* bo = (const float*)d_in[8];

  bf16* ws  = (bf16*)d_ws;
  bf16* WtQ = ws;
  bf16* WtK = WtQ + (size_t)C_ * C_;
  bf16* WtV = WtK + (size_t)C_ * C_;
  bf16* WtO = WtV + (size_t)C_ * C_;
  bf16* xb  = WtO + (size_t)C_ * C_;           // [4096][1024]
  bf16* qkb = xb + (size_t)M_ * C_;            // [4096][2048]  (Q | K)
  bf16* vtb = qkb + (size_t)M_ * 2 * C_;       // [32][64][2048] (kt-interleaved)
  bf16* yb  = vtb + (size_t)M_ * C_;           // [4096][1024]
  bf16* pob = yb + (size_t)M_ * C_;            // [512][8192] packed partial O
  float* plb = (float*)(pob + (size_t)512 * 8192);

  PrepArgs pp;
  pp.w[0] = Wq; pp.w[1] = Wk; pp.w[2] = Wv; pp.w[3] = Wo;
  pp.wt[0] = WtQ; pp.wt[1] = WtK; pp.wt[2] = WtV; pp.wt[3] = WtO;
  pp.x = x; pp.xb = xb;
  prep<<<dim3(4096 + M_ * C_ / (256 * 8)), 256, 0, stream>>>(pp);

  GQ gq;
  gq.A = xb; gq.Bt = WtQ;
  gq.bias[0] = bq; gq.bias[1] = bk; gq.bias[2] = bv;
  gq.Cout = qkb; gq.vt = vtb; gq.N = 2 * C_; gq.K = C_;
  gemm128<<<dim3(24, 32), 256, 0, stream>>>(gq);

  attn8<<<dim3(768), 512, 0, stream>>>(qkb, vtb, yb, pob, plb);
  combine<<<dim3(32 * 8), 256, 0, stream>>>(pob, plb, yb);

  gemm_out<<<dim3(8, 64), 256, 0, stream>>>(yb, WtO, bo, (float*)d_out);
}